// Round 8
// baseline (424.550 us; speedup 1.0000x reference)
//
#include <hip/hip_runtime.h>

#define NN 50000
#define NE 800000
#define CAP 64          // padded CSR slots per node (max deg_in ~40 for Poisson(16))

// ---- bucketed build parameters ----
#define NPB 128         // nodes per bucket (dst >> 7)
#define NBKT 391        // ceil(NN / NPB)
#define NBKT_PAD 512
#define BCAP 3072       // partition slots per bucket (mean 2048, sigma ~45 -> 22 sigma margin)
#define CHUNK 4096      // edges per partition block
#define GW4E 12500      // wave-per-node gather blocks (NN/4)

typedef unsigned short u16;
typedef unsigned int u32;
typedef unsigned long long u64;
typedef __attribute__((ext_vector_type(8))) short bf8_t;   // 8 x bf16 (4 VGPRs)
typedef __attribute__((ext_vector_type(4))) float f4_t;    // 4 x f32 acc

__device__ __forceinline__ u16 f2b(float f) {              // RNE fp32 -> bf16
    unsigned u = __float_as_uint(f);
    unsigned r = u + 0x7FFF + ((u >> 16) & 1);
    return (u16)(r >> 16);
}

// ---------------- pack helper: W (fp32 [K][192]) -> MFMA B-fragment bf16 ----------------
__device__ __forceinline__ void pack_one(const float* __restrict__ W, u16* __restrict__ Wp,
                                         int idx, int KS) {
    int l = idx & 63;
    int s = (idx >> 6) % KS;
    int t = (idx >> 6) / KS;
    int col = t * 16 + (l & 15);
    int krow = s * 32 + ((l >> 4) * 8);
    u16 tmp[8] __attribute__((aligned(16)));
#pragma unroll
    for (int j = 0; j < 8; ++j) tmp[j] = f2b(W[(size_t)(krow + j) * 192 + col]);
    *(uint4*)(Wp + (size_t)idx * 8) = *(const uint4*)tmp;
}

// ------- pass A (union): LDS-staged partition of edges into dst-buckets + weight pack ---
__global__ __launch_bounds__(256) void partition_pack_k(
    const int* __restrict__ src, const int* __restrict__ dst,
    int* __restrict__ deg_out, int* __restrict__ bktc,
    u64* __restrict__ part, int E,
    const float* __restrict__ Wc0, const float* __restrict__ Wc1,
    const float* __restrict__ Wl0,
    u16* __restrict__ Wp0, u16* __restrict__ Wp1, u16* __restrict__ Wp2) {
    const int PBLK = (E + CHUNK - 1) / CHUNK;
    if (blockIdx.x >= PBLK) {           // ---- pack path ----
        int idx = (blockIdx.x - PBLK) * 256 + threadIdx.x;
        if (idx < 3072) pack_one(Wc0, Wp0, idx, 4);                 // 12*4*64
        else if (idx < 7680) pack_one(Wc1, Wp1, idx - 3072, 6);     // 12*6*64
        else if (idx < 12288) pack_one(Wl0, Wp2, idx - 7680, 6);
        return;
    }

    __shared__ unsigned cnt[NBKT_PAD];
    __shared__ unsigned base[NBKT_PAD];
    __shared__ unsigned cur[NBKT_PAD];
    __shared__ unsigned gbase[NBKT_PAD];
    __shared__ unsigned wtot[4];
    __shared__ u64 staged[CHUNK];

    const int tid = threadIdx.x;
    const int lane = tid & 63;
    const int wid = tid >> 6;
    const int e0 = blockIdx.x * CHUNK;
    const int n = min(CHUNK, E - e0);

    for (int i = tid; i < NBKT_PAD; i += 256) cnt[i] = 0;
    __syncthreads();

    for (int i = tid; i < n; i += 256) {
        int d = dst[e0 + i];
        atomicAdd(&cnt[d >> 7], 1u);
    }
    __syncthreads();

    {
        unsigned a = cnt[2 * tid];
        unsigned b = cnt[2 * tid + 1];
        unsigned ps = a + b;
        unsigned inc = ps;
#pragma unroll
        for (int d = 1; d < 64; d <<= 1) {
            unsigned v = __shfl_up(inc, d);
            if (lane >= d) inc += v;
        }
        if (lane == 63) wtot[wid] = inc;
        __syncthreads();
        unsigned wb = 0;
#pragma unroll
        for (int k = 0; k < 4; ++k) wb += (k < wid) ? wtot[k] : 0;
        unsigned eb = wb + inc - ps;
        base[2 * tid] = eb;
        base[2 * tid + 1] = eb + a;
        cur[2 * tid] = eb;
        cur[2 * tid + 1] = eb + a;
    }
    __syncthreads();

    for (int i = tid; i < n; i += 256) {
        int e = e0 + i;
        int d = dst[e];
        int s = src[e];
        atomicAdd(deg_out + s, 1);
        unsigned p = atomicAdd(&cur[d >> 7], 1u);
        staged[p] = ((u64)(unsigned)e << 32) | (((u32)d << 16) | (u32)s);
    }
    __syncthreads();

    for (int b = tid; b < NBKT; b += 256) {
        unsigned c = cur[b] - base[b];
        if (c) gbase[b] = (unsigned)atomicAdd(&bktc[b], (int)c);
    }
    __syncthreads();

    for (int i = tid; i < n; i += 256) {
        u64 v = staged[i];
        int b = (int)((v >> 16) & 0xffffu) >> 7;
        unsigned idx = gbase[b] + ((unsigned)i - base[b]);
        if (idx < BCAP) part[(size_t)b * BCAP + idx] = v;
    }
}

// ---------------- pass B: per-bucket CSR fill + degree-derived scalars ----------------
__global__ __launch_bounds__(256) void fill_k(
    const u64* __restrict__ part, const int* __restrict__ bktc,
    const int* __restrict__ deg_out,
    int* __restrict__ csr_src, int* __restrict__ csr_eid,
    int* __restrict__ din,
    float* __restrict__ inv_in, float* __restrict__ inv_out,
    float* __restrict__ inv_mean, float* __restrict__ bcoef, int n) {
    __shared__ unsigned cur[NPB];
    const int tid = threadIdx.x;
    const int b = blockIdx.x;
    const int node0 = b << 7;
    if (tid < NPB) cur[tid] = 0;
    __syncthreads();

    const int cnt = min(bktc[b], BCAP);
    const u64* p = part + (size_t)b * BCAP;
    for (int i = tid; i < cnt; i += 256) {
        u64 v = p[i];
        int s = (int)(v & 0xffffu);
        int d = (int)((v >> 16) & 0xffffu);
        int e = (int)(v >> 32);
        unsigned q = atomicAdd(&cur[d & (NPB - 1)], 1u);
        if (q < CAP) {
            csr_src[((size_t)d << 6) + q] = s;
            csr_eid[((size_t)d << 6) + q] = e;
        }
    }
    __syncthreads();
    if (tid < NPB) {
        int node = node0 + tid;
        if (node < n) {
            unsigned cq = min(cur[tid], (unsigned)CAP);
            din[node] = (int)cq;
            int end = (cq <= 32u) ? 32 : 64;
            for (int q = (int)cq; q < end; ++q)
                csr_eid[((size_t)node << 6) + q] = 0;
            float di = fmaxf((float)cq, 1.0f);
            float dq = fmaxf((float)deg_out[node], 1.0f);
            inv_in[node]   = 1.0f / sqrtf(di);
            inv_out[node]  = 1.0f / sqrtf(dq);
            inv_mean[node] = 1.0f / di;
            bcoef[node]    = (cq > 0u) ? 1.0f : 0.0f;
        }
    }
}

// -------- union kernel: edge layer (gather + 32x32 We, GW4E blocks) | node GEMM --------
__global__ __launch_bounds__(256) void edge_node_k(
    const float* __restrict__ ef, const int* __restrict__ csr_eid,
    const int* __restrict__ deg,
    const float* __restrict__ inv_mean, const float* __restrict__ bcoef,
    const float* __restrict__ inv_out,
    const float* __restrict__ We, const float* __restrict__ be,
    const float* __restrict__ nf, const float* __restrict__ Wn,
    const float* __restrict__ bn,
    u16* __restrict__ h0, int n) {
    __shared__ float sv[4][32];
    __shared__ float s_in[32 * 64];
    const int tid = threadIdx.x;
    const int lane = tid & 63;
    const int w = tid >> 6;

    if (blockIdx.x < GW4E) {
        // ---- edge path (wave per node) ----
        const int node = __builtin_amdgcn_readfirstlane(blockIdx.x * 4 + w);
        const int beg = node << 6;
        const int cnt = deg[node];
        const int g = lane >> 4;            // row group 0..3
        const int c = lane & 15;            // float2 column pair

        float ax = 0.0f, ay = 0.0f;
        {
            int eidv[8];
#pragma unroll
            for (int j = 0; j < 8; ++j) eidv[j] = csr_eid[beg + 4 * j + g];
            float2 v[8];
#pragma unroll
            for (int j = 0; j < 8; ++j)
                v[j] = *(const float2*)(ef + (size_t)eidv[j] * 32 + 2 * c);
#pragma unroll
            for (int j = 0; j < 8; ++j)
                if (4 * j + g < cnt) { ax += v[j].x; ay += v[j].y; }
        }
        if (cnt > 32) {                     // rare, wave-uniform
            int eidv[8];
#pragma unroll
            for (int j = 0; j < 8; ++j) eidv[j] = csr_eid[beg + 32 + 4 * j + g];
            float2 v[8];
#pragma unroll
            for (int j = 0; j < 8; ++j)
                v[j] = *(const float2*)(ef + (size_t)eidv[j] * 32 + 2 * c);
#pragma unroll
            for (int j = 0; j < 8; ++j)
                if (32 + 4 * j + g < cnt) { ax += v[j].x; ay += v[j].y; }
        }
        ax += __shfl_down(ax, 16); ay += __shfl_down(ay, 16);
        ax += __shfl_down(ax, 32); ay += __shfl_down(ay, 32);
        if (lane < 16) {
            float im = inv_mean[node];
            float2 o; o.x = ax * im; o.y = ay * im;
            *(float2*)&sv[w][2 * c] = o;    // wave-internal LDS: lgkmcnt ordered
        }
        int col = lane & 31;
        float s = 0.0f;
#pragma unroll 8
        for (int k = 0; k < 32; ++k)
            s = fmaf(sv[w][k], We[k * 32 + col], s);
        if (lane < 32) {
            float v = fmaxf(s + be[col] * bcoef[node], 0.0f) * inv_out[node];
            h0[(size_t)node * 128 + col] = f2b(v);
        }
        return;
    }

    // ---- node GEMM path (64 -> 96), 32 rows per block ----
    const int row0 = (blockIdx.x - GW4E) * 32;
    for (int i = tid; i < 512; i += 256) {      // 32 rows x 16 float4
        int m = i >> 4;
        int kv = i & 15;
        int row = min(row0 + m, n - 1);
        float4 v = *(const float4*)(nf + (size_t)row * 64 + kv * 4);
        *(float4*)(s_in + m * 64 + kv * 4) = v;
    }
    __syncthreads();

    int f0 = lane, f1 = lane + 64;
    bool fok1 = (f1 < 96);
    int ff1 = fok1 ? f1 : 0;
    float bv0 = bn[f0], bv1 = bn[ff1];

    const float* s_my = s_in + w * 8 * 64;
    float acc0[8], acc1[8];
#pragma unroll
    for (int m = 0; m < 8; ++m) { acc0[m] = 0.0f; acc1[m] = 0.0f; }

    for (int k = 0; k < 64; k += 4) {
        float wv[4][2];
#pragma unroll
        for (int j = 0; j < 4; ++j) {
            wv[j][0] = Wn[(k + j) * 96 + f0];
            wv[j][1] = Wn[(k + j) * 96 + ff1];
        }
#pragma unroll
        for (int m = 0; m < 8; ++m) {
            float4 a = *(const float4*)(s_my + m * 64 + k);
            acc0[m] = fmaf(a.x, wv[0][0], acc0[m]);
            acc0[m] = fmaf(a.y, wv[1][0], acc0[m]);
            acc0[m] = fmaf(a.z, wv[2][0], acc0[m]);
            acc0[m] = fmaf(a.w, wv[3][0], acc0[m]);
            acc1[m] = fmaf(a.x, wv[0][1], acc1[m]);
            acc1[m] = fmaf(a.y, wv[1][1], acc1[m]);
            acc1[m] = fmaf(a.z, wv[2][1], acc1[m]);
            acc1[m] = fmaf(a.w, wv[3][1], acc1[m]);
        }
    }

#pragma unroll
    for (int m = 0; m < 8; ++m) {
        int row = row0 + w * 8 + m;
        if (row < n) {
            float pm = inv_out[row];
            float v0 = fmaxf(acc0[m] + bv0, 0.0f) * pm;
            h0[(size_t)row * 128 + 32 + f0] = f2b(v0);
            if (fok1) {
                float v1 = fmaxf(acc1[m] + bv1, 0.0f) * pm;
                h0[(size_t)row * 128 + 32 + f1] = f2b(v1);
            }
        }
    }
}

// ------------- fused conv0: 16 waves, wave-per-node gather -> LDS -> MFMA ---------------
// Same 50000 gather waves as the standalone kernel (r6's mistake was 12500 waves x 4
// serial nodes). Gather math/order bit-identical; MFMA tiles redistributed over waves.
__global__ __launch_bounds__(1024) void conv0_k(
    const u16* __restrict__ h0, const int* __restrict__ csr,
    const int* __restrict__ deg, const float* __restrict__ inv_in,
    const u16* __restrict__ Wp, const float* __restrict__ bias,
    const float* __restrict__ posts, u16* __restrict__ h1) {
    constexpr int KS = 4, ST = 136;   // +8 u16 pad -> 2-way bank alias (free)
    __shared__ u16 tile[16 * ST];
    const int tid = threadIdx.x;
    const int lane = tid & 63;
    const int w = tid >> 6;           // 0..15
    const int row0 = blockIdx.x * 16;
    const int node = __builtin_amdgcn_readfirstlane(row0 + w);
    const int beg = node << 6;
    const int cnt = deg[node];
    const int off = lane * 2;

    // ---- gather (one node per wave, 16-deep batches, no prefetch) ----
    float a0 = 0.0f, a1 = 0.0f;
    {
        const int nb = cnt >> 4;
        for (int b = 0; b < nb; ++b) {
            int idx[16];
#pragma unroll
            for (int j = 0; j < 16; ++j) idx[j] = csr[beg + b * 16 + j];
            unsigned lv[16];
#pragma unroll
            for (int j = 0; j < 16; ++j)
                lv[j] = *(const unsigned*)(h0 + (size_t)idx[j] * 128 + off);
#pragma unroll
            for (int j = 0; j < 16; ++j) {
                a0 += __uint_as_float(lv[j] << 16);
                a1 += __uint_as_float(lv[j] & 0xffff0000u);
            }
        }
        int tb = beg + (nb << 4);
        int rem = cnt & 15;
        if (rem >= 8) {
            int ti[8];
#pragma unroll
            for (int j = 0; j < 8; ++j) ti[j] = csr[tb + j];
            unsigned lv[8];
#pragma unroll
            for (int j = 0; j < 8; ++j)
                lv[j] = *(const unsigned*)(h0 + (size_t)ti[j] * 128 + off);
#pragma unroll
            for (int j = 0; j < 8; ++j) {
                a0 += __uint_as_float(lv[j] << 16);
                a1 += __uint_as_float(lv[j] & 0xffff0000u);
            }
            tb += 8; rem -= 8;
        }
        for (int t = 0; t < rem; ++t) {
            unsigned u = *(const unsigned*)(h0 + (size_t)csr[tb + t] * 128 + off);
            a0 += __uint_as_float(u << 16);
            a1 += __uint_as_float(u & 0xffff0000u);
        }
    }
    {
        float sc = inv_in[node];
        unsigned o = (unsigned)f2b(a0 * sc) | ((unsigned)f2b(a1 * sc) << 16);
        *(unsigned*)&tile[w * ST + off] = o;
    }
    __syncthreads();

    // ---- MFMA: waves 0..11, one 16-col tile each ----
    if (w < 12) {
        const int kbase = (lane >> 4) * 8;
        f4_t acc = (f4_t){0.f, 0.f, 0.f, 0.f};
        const u16* ap = tile + (lane & 15) * ST + kbase;
#pragma unroll
        for (int s = 0; s < KS; ++s) {
            bf8_t af = *(const bf8_t*)(ap + s * 32);
            bf8_t bf = *(const bf8_t*)(Wp + (size_t)((w * KS + s) * 64 + lane) * 8);
            acc = __builtin_amdgcn_mfma_f32_16x16x32_bf16(af, bf, acc, 0, 0, 0);
        }
        const int drow = row0 + (lane >> 4) * 4;
        const int dcol = lane & 15;
        const int col = w * 16 + dcol;
        float bv = bias[col];
#pragma unroll
        for (int r = 0; r < 4; ++r) {
            float v = fmaxf(acc[r] + bv, 0.0f) * posts[drow + r];
            h1[(size_t)(drow + r) * 192 + col] = f2b(v);
        }
    }
}

// --- fused conv1: 16 waves, wave-per-node gather -> LDS -> GEMM1+GEMM2+head -> out ------
__global__ __launch_bounds__(1024) void conv1_k(
    const u16* __restrict__ h1, const int* __restrict__ csr,
    const int* __restrict__ deg, const float* __restrict__ inv_in,
    const u16* __restrict__ Wp1, const float* __restrict__ b1,
    const u16* __restrict__ Wp2, const float* __restrict__ b2,
    const float* __restrict__ Wo, const float* __restrict__ bo,
    float* __restrict__ out, int n) {
    constexpr int KS = 6, S = 200;
    __shared__ u16 tileA[16 * S];
    __shared__ float sbuf[16 * S];
    __shared__ float s_head[16][17][2];

    const int tid = threadIdx.x;
    const int lane = tid & 63;
    const int w = tid >> 6;           // 0..15
    const int row0 = blockIdx.x * 16;
    const int node = __builtin_amdgcn_readfirstlane(row0 + w);
    const int beg = node << 6;
    const int cnt = deg[node];
    const int goff = (lane < 48 ? lane : 47) * 4;
    const int kbase = (lane >> 4) * 8;
    const int drow = (lane >> 4) * 4;
    const int dcol = lane & 15;

    // ---- gather (one node per wave, 16-deep batches, no prefetch) ----
    {
        float acc4[4];
#pragma unroll
        for (int j = 0; j < 4; ++j) acc4[j] = 0.0f;
        const int nb = cnt >> 4;
        for (int b = 0; b < nb; ++b) {
            int idx[16];
#pragma unroll
            for (int j = 0; j < 16; ++j) idx[j] = csr[beg + b * 16 + j];
            unsigned lv[16][2];
#pragma unroll
            for (int j = 0; j < 16; ++j) {
                uint2 t = *(const uint2*)(h1 + (size_t)idx[j] * 192 + goff);
                lv[j][0] = t.x; lv[j][1] = t.y;
            }
#pragma unroll
            for (int j = 0; j < 16; ++j)
#pragma unroll
                for (int q = 0; q < 2; ++q) {
                    unsigned u = lv[j][q];
                    acc4[2 * q]     += __uint_as_float(u << 16);
                    acc4[2 * q + 1] += __uint_as_float(u & 0xffff0000u);
                }
        }
        int tb = beg + (nb << 4);
        int rem = cnt & 15;
        if (rem >= 8) {
            int ti[8];
#pragma unroll
            for (int j = 0; j < 8; ++j) ti[j] = csr[tb + j];
            unsigned lv[8][2];
#pragma unroll
            for (int j = 0; j < 8; ++j) {
                uint2 t = *(const uint2*)(h1 + (size_t)ti[j] * 192 + goff);
                lv[j][0] = t.x; lv[j][1] = t.y;
            }
#pragma unroll
            for (int j = 0; j < 8; ++j)
#pragma unroll
                for (int q = 0; q < 2; ++q) {
                    unsigned u = lv[j][q];
                    acc4[2 * q]     += __uint_as_float(u << 16);
                    acc4[2 * q + 1] += __uint_as_float(u & 0xffff0000u);
                }
            tb += 8; rem -= 8;
        }
        for (int t = 0; t < rem; ++t) {
            const unsigned* p = (const unsigned*)(h1 + (size_t)csr[tb + t] * 192 + goff);
#pragma unroll
            for (int q = 0; q < 2; ++q) {
                unsigned u = p[q];
                acc4[2 * q]     += __uint_as_float(u << 16);
                acc4[2 * q + 1] += __uint_as_float(u & 0xffff0000u);
            }
        }
        if (lane < 48) {
            float sc = inv_in[node];
            uint2 o;
            o.x = (unsigned)f2b(acc4[0] * sc) | ((unsigned)f2b(acc4[1] * sc) << 16);
            o.y = (unsigned)f2b(acc4[2] * sc) | ((unsigned)f2b(acc4[3] * sc) << 16);
            *(uint2*)&tileA[w * S + goff] = o;
        }
    }
    __syncthreads();

    // ---- GEMM 1: tileA (LDS bf16) @ W1 -> h2 (LDS bf16) ----
    u16* h2 = (u16*)sbuf;
    if (w < 12) {
        f4_t acc = (f4_t){0.f, 0.f, 0.f, 0.f};
        const u16* ap = tileA + (lane & 15) * S + kbase;
#pragma unroll
        for (int s = 0; s < KS; ++s) {
            bf8_t af = *(const bf8_t*)(ap + s * 32);
            bf8_t bf = *(const bf8_t*)(Wp1 + (size_t)((w * KS + s) * 64 + lane) * 8);
            acc = __builtin_amdgcn_mfma_f32_16x16x32_bf16(af, bf, acc, 0, 0, 0);
        }
        int col = w * 16 + dcol;
        float bv = b1[col];
#pragma unroll
        for (int r = 0; r < 4; ++r)
            h2[(drow + r) * S + col] = f2b(fmaxf(acc[r] + bv, 0.0f));
    }
    __syncthreads();

    // ---- GEMM 2: h2 (LDS bf16) @ W2 ----
    f4_t acc2 = (f4_t){0.f, 0.f, 0.f, 0.f};
    if (w < 12) {
        const u16* hp = h2 + (lane & 15) * S + kbase;
#pragma unroll
        for (int s = 0; s < KS; ++s) {
            bf8_t af = *(const bf8_t*)(hp + s * 32);
            bf8_t bf = *(const bf8_t*)(Wp2 + (size_t)((w * KS + s) * 64 + lane) * 8);
            acc2 = __builtin_amdgcn_mfma_f32_16x16x32_bf16(af, bf, acc2, 0, 0, 0);
        }
    }
    __syncthreads();  // all h2 reads done before overwriting sbuf as f32

    // h3 = relu(acc2 + b2) -> LDS (f32)
    if (w < 12) {
        int col = w * 16 + dcol;
        float bv = b2[col];
#pragma unroll
        for (int r = 0; r < 4; ++r)
            sbuf[(drow + r) * S + col] = fmaxf(acc2[r] + bv, 0.0f);
    }
    __syncthreads();

    // ---- head: out = h3 @ Wo + bo ----
    if (tid < 256) {
        int r = tid >> 4;
        int seg = tid & 15;
        const float* hr = sbuf + r * S + seg * 12;
        const float* wor = Wo + seg * 24;
        float p0 = 0.0f, p1 = 0.0f;
#pragma unroll
        for (int c = 0; c < 12; ++c) {
            float hv = hr[c];
            p0 = fmaf(hv, wor[c * 2 + 0], p0);
            p1 = fmaf(hv, wor[c * 2 + 1], p1);
        }
        s_head[r][seg][0] = p0;
        s_head[r][seg][1] = p1;
    }
    __syncthreads();
    if (tid < 32) {
        int r = tid >> 1, c = tid & 1;
        float sum = bo[c];
#pragma unroll
        for (int g = 0; g < 16; ++g) sum += s_head[r][g][c];
        int row = row0 + r;
        if (row < n) out[(size_t)row * 2 + c] = sum;
    }
}

extern "C" void kernel_launch(void* const* d_in, const int* in_sizes, int n_in,
                              void* d_out, int out_size, void* d_ws, size_t ws_size,
                              hipStream_t stream) {
    const float* node_feats = (const float*)d_in[0];   // [N,64]
    const float* edge_feats = (const float*)d_in[1];   // [E,32]
    const float* Wn  = (const float*)d_in[2];          // [64,96]
    const float* bn  = (const float*)d_in[3];
    const float* We  = (const float*)d_in[4];          // [32,32]
    const float* be  = (const float*)d_in[5];
    const float* Wc0 = (const float*)d_in[6];          // [128,192]
    const float* bc0 = (const float*)d_in[7];
    const float* Wc1 = (const float*)d_in[8];          // [192,192]
    const float* bc1 = (const float*)d_in[9];
    const float* Wl0 = (const float*)d_in[10];         // [192,192]
    const float* bl0 = (const float*)d_in[11];
    const float* Wo  = (const float*)d_in[12];         // [192,2]
    const float* bo  = (const float*)d_in[13];
    const int* src = (const int*)d_in[14];
    const int* dst = (const int*)d_in[15];
    float* out = (float*)d_out;

    const int N = NN, E = NE;

    // ---- workspace layout (16B-aligned sections) ----
    int* dout      = (int*)d_ws;               // N (zeroed) -> deg_out
    int* bktc      = dout + N;                 // NBKT_PAD (zeroed) -> bucket cursors
    int* din       = bktc + NBKT_PAD;          // N deg_in (written by fill_k)
    int* csr_src   = din + N;                  // CAP*N ints (padded CSR, src ids)
    int* csr_eid   = csr_src + (size_t)CAP * N;// CAP*N ints (padded CSR, edge ids; 0-pad)
    float* inv_in   = (float*)(csr_eid + (size_t)CAP * N);  // N
    float* inv_out  = inv_in + N;              // N
    float* inv_mean = inv_out + N;             // N
    float* bcoef    = inv_mean + N;            // N
    u16* h0   = (u16*)(bcoef + N);             // [N,128] bf16 (x inv_out)
    u16* h1   = h0 + (size_t)128 * N;          // [N,192] bf16 (x inv_out)
    u16* Wp0  = h1 + (size_t)192 * N;          // 128*192
    u16* Wp1  = Wp0 + 128 * 192;               // 192*192
    u16* Wp2  = Wp1 + 192 * 192;               // 192*192
    // partition buffer (9.6 MB u64) aliases h1 (19.2 MB): consumed by fill_k long
    // before conv0_k writes h1. h1 offset is a 16B multiple -> u64-aligned.
    u64* part = (u64*)h1;

    hipMemsetAsync(d_ws, 0, (size_t)(N + NBKT_PAD) * sizeof(int), stream);

    const int PBLK = (E + CHUNK - 1) / CHUNK;  // 196 partition blocks
    const int GB16 = N / 16;                   // fused conv grid (3125, exact)
    const int GB32 = (N + 31) / 32;            // node-GEMM blocks (1563)

    // partition + weight pack (one launch)
    partition_pack_k<<<dim3(PBLK + 48), dim3(256), 0, stream>>>(
        src, dst, dout, bktc, part, E, Wc0, Wc1, Wl0, Wp0, Wp1, Wp2);
    // per-bucket CSR fill + inv scalars
    fill_k<<<dim3(NBKT), dim3(256), 0, stream>>>(part, bktc, dout, csr_src, csr_eid,
                                                 din, inv_in, inv_out, inv_mean, bcoef, N);

    // edge layer (wave-per-node gather + We) | node GEMM (64->96) -- one launch
    edge_node_k<<<dim3(GW4E + GB32), dim3(256), 0, stream>>>(
        edge_feats, csr_eid, din, inv_mean, bcoef, inv_out, We, be,
        node_feats, Wn, bn, h0, N);

    // fused conv0: 16-wave blocks, wave-per-node gather + MFMA 128->192 -> h1
    conv0_k<<<dim3(GB16), dim3(1024), 0, stream>>>(h0, csr_src, din, inv_in,
                                                   Wp0, bc0, inv_out, h1);
    // fused conv1: 16-wave blocks, wave-per-node gather + GEMM1+GEMM2+head -> out
    conv1_k<<<dim3(GB16), dim3(1024), 0, stream>>>(h1, csr_src, din, inv_in,
                                                   Wp1, bc1, Wp2, bl0, Wo, bo, out, N);
}

// Round 9
// 404.701 us; speedup vs baseline: 1.0490x; 1.0490x over previous
//
#include <hip/hip_runtime.h>

#define NN 50000
#define NE 800000
#define CAP 64          // padded CSR slots per node (max deg_in ~40 for Poisson(16))

// ---- bucketed build parameters ----
#define NPB 128         // nodes per bucket (dst >> 7)
#define NBKT 391        // ceil(NN / NPB)
#define NBKT_PAD 512
#define BCAP 3072       // partition slots per bucket (mean 2048, sigma ~45 -> 22 sigma margin)
#define CHUNK 4096      // edges per partition block
#define GW4E 12500      // wave-per-node gather blocks (NN/4)
#define CONVB 3125      // ef->bf16 convert blocks (E*32/8 uint4 / 1024 per block)

typedef unsigned short u16;
typedef unsigned int u32;
typedef unsigned long long u64;
typedef __attribute__((ext_vector_type(8))) short bf8_t;   // 8 x bf16 (4 VGPRs)
typedef __attribute__((ext_vector_type(4))) float f4_t;    // 4 x f32 acc

__device__ __forceinline__ u16 f2b(float f) {              // RNE fp32 -> bf16
    unsigned u = __float_as_uint(f);
    unsigned r = u + 0x7FFF + ((u >> 16) & 1);
    return (u16)(r >> 16);
}

// ---------------- pack helper: W (fp32 [K][192]) -> MFMA B-fragment bf16 ----------------
__device__ __forceinline__ void pack_one(const float* __restrict__ W, u16* __restrict__ Wp,
                                         int idx, int KS) {
    int l = idx & 63;
    int s = (idx >> 6) % KS;
    int t = (idx >> 6) / KS;
    int col = t * 16 + (l & 15);
    int krow = s * 32 + ((l >> 4) * 8);
    u16 tmp[8] __attribute__((aligned(16)));
#pragma unroll
    for (int j = 0; j < 8; ++j) tmp[j] = f2b(W[(size_t)(krow + j) * 192 + col]);
    *(uint4*)(Wp + (size_t)idx * 8) = *(const uint4*)tmp;
}

// -- pass A (union): edge partition | weight pack | ef->bf16 stream (all disjoint work) --
// Partition blocks are latency/atomic-bound and leave BW idle; the convert blocks soak it.
__global__ __launch_bounds__(256) void partition_pack_k(
    const int* __restrict__ src, const int* __restrict__ dst,
    int* __restrict__ deg_out, int* __restrict__ bktc,
    u64* __restrict__ part, int E,
    const float* __restrict__ Wc0, const float* __restrict__ Wc1,
    const float* __restrict__ Wl0,
    u16* __restrict__ Wp0, u16* __restrict__ Wp1, u16* __restrict__ Wp2,
    const float* __restrict__ ef, u16* __restrict__ efh) {
    const int PBLK = (E + CHUNK - 1) / CHUNK;
    const int tid = threadIdx.x;

    if (blockIdx.x >= PBLK + 48) {      // ---- ef -> bf16 convert path ----
        const int ob = (blockIdx.x - PBLK - 48) * 1024;   // uint4 outputs per block
#pragma unroll
        for (int it = 0; it < 4; ++it) {
            int oi = ob + it * 256 + tid;                 // [0, 3.2M)
            float4 a0 = *(const float4*)(ef + (size_t)oi * 8);
            float4 a1 = *(const float4*)(ef + (size_t)oi * 8 + 4);
            u16 tmp[8] __attribute__((aligned(16)));
            tmp[0] = f2b(a0.x); tmp[1] = f2b(a0.y); tmp[2] = f2b(a0.z); tmp[3] = f2b(a0.w);
            tmp[4] = f2b(a1.x); tmp[5] = f2b(a1.y); tmp[6] = f2b(a1.z); tmp[7] = f2b(a1.w);
            *(uint4*)(efh + (size_t)oi * 8) = *(const uint4*)tmp;
        }
        return;
    }
    if (blockIdx.x >= PBLK) {           // ---- pack path ----
        int idx = (blockIdx.x - PBLK) * 256 + tid;
        if (idx < 3072) pack_one(Wc0, Wp0, idx, 4);                 // 12*4*64
        else if (idx < 7680) pack_one(Wc1, Wp1, idx - 3072, 6);     // 12*6*64
        else if (idx < 12288) pack_one(Wl0, Wp2, idx - 7680, 6);
        return;
    }

    __shared__ unsigned cnt[NBKT_PAD];
    __shared__ unsigned base[NBKT_PAD];
    __shared__ unsigned cur[NBKT_PAD];
    __shared__ unsigned gbase[NBKT_PAD];
    __shared__ unsigned wtot[4];
    __shared__ u64 staged[CHUNK];

    const int lane = tid & 63;
    const int wid = tid >> 6;
    const int e0 = blockIdx.x * CHUNK;
    const int n = min(CHUNK, E - e0);

    for (int i = tid; i < NBKT_PAD; i += 256) cnt[i] = 0;
    __syncthreads();

    for (int i = tid; i < n; i += 256) {
        int d = dst[e0 + i];
        atomicAdd(&cnt[d >> 7], 1u);
    }
    __syncthreads();

    {
        unsigned a = cnt[2 * tid];
        unsigned b = cnt[2 * tid + 1];
        unsigned ps = a + b;
        unsigned inc = ps;
#pragma unroll
        for (int d = 1; d < 64; d <<= 1) {
            unsigned v = __shfl_up(inc, d);
            if (lane >= d) inc += v;
        }
        if (lane == 63) wtot[wid] = inc;
        __syncthreads();
        unsigned wb = 0;
#pragma unroll
        for (int k = 0; k < 4; ++k) wb += (k < wid) ? wtot[k] : 0;
        unsigned eb = wb + inc - ps;
        base[2 * tid] = eb;
        base[2 * tid + 1] = eb + a;
        cur[2 * tid] = eb;
        cur[2 * tid + 1] = eb + a;
    }
    __syncthreads();

    for (int i = tid; i < n; i += 256) {
        int e = e0 + i;
        int d = dst[e];
        int s = src[e];
        atomicAdd(deg_out + s, 1);
        unsigned p = atomicAdd(&cur[d >> 7], 1u);
        staged[p] = ((u64)(unsigned)e << 32) | (((u32)d << 16) | (u32)s);
    }
    __syncthreads();

    for (int b = tid; b < NBKT; b += 256) {
        unsigned c = cur[b] - base[b];
        if (c) gbase[b] = (unsigned)atomicAdd(&bktc[b], (int)c);
    }
    __syncthreads();

    for (int i = tid; i < n; i += 256) {
        u64 v = staged[i];
        int b = (int)((v >> 16) & 0xffffu) >> 7;
        unsigned idx = gbase[b] + ((unsigned)i - base[b]);
        if (idx < BCAP) part[(size_t)b * BCAP + idx] = v;
    }
}

// ---------------- pass B: per-bucket CSR fill + degree-derived scalars ----------------
__global__ __launch_bounds__(256) void fill_k(
    const u64* __restrict__ part, const int* __restrict__ bktc,
    const int* __restrict__ deg_out,
    int* __restrict__ csr_src, int* __restrict__ csr_eid,
    int* __restrict__ din,
    float* __restrict__ inv_in, float* __restrict__ inv_out,
    float* __restrict__ inv_mean, float* __restrict__ bcoef, int n) {
    __shared__ unsigned cur[NPB];
    const int tid = threadIdx.x;
    const int b = blockIdx.x;
    const int node0 = b << 7;
    if (tid < NPB) cur[tid] = 0;
    __syncthreads();

    const int cnt = min(bktc[b], BCAP);
    const u64* p = part + (size_t)b * BCAP;
    for (int i = tid; i < cnt; i += 256) {
        u64 v = p[i];
        int s = (int)(v & 0xffffu);
        int d = (int)((v >> 16) & 0xffffu);
        int e = (int)(v >> 32);
        unsigned q = atomicAdd(&cur[d & (NPB - 1)], 1u);
        if (q < CAP) {
            csr_src[((size_t)d << 6) + q] = s;
            csr_eid[((size_t)d << 6) + q] = e;
        }
    }
    __syncthreads();
    if (tid < NPB) {
        int node = node0 + tid;
        if (node < n) {
            unsigned cq = min(cur[tid], (unsigned)CAP);
            din[node] = (int)cq;
            int end = (cq <= 32u) ? 32 : 64;
            for (int q = (int)cq; q < end; ++q)
                csr_eid[((size_t)node << 6) + q] = 0;
            float di = fmaxf((float)cq, 1.0f);
            float dq = fmaxf((float)deg_out[node], 1.0f);
            inv_in[node]   = 1.0f / sqrtf(di);
            inv_out[node]  = 1.0f / sqrtf(dq);
            inv_mean[node] = 1.0f / di;
            bcoef[node]    = (cq > 0u) ? 1.0f : 0.0f;
        }
    }
}

// ---- union kernel: edge layer (bf16 gather + 32x32 We, GW4E blocks) | node GEMM --------
// Edge rows are now bf16 (64 B): half the random cache-line transactions of fp32.
__global__ __launch_bounds__(256) void edge_node_k(
    const u16* __restrict__ efh, const int* __restrict__ csr_eid,
    const int* __restrict__ deg,
    const float* __restrict__ inv_mean, const float* __restrict__ bcoef,
    const float* __restrict__ inv_out,
    const float* __restrict__ We, const float* __restrict__ be,
    const float* __restrict__ nf, const float* __restrict__ Wn,
    const float* __restrict__ bn,
    u16* __restrict__ h0, int n) {
    __shared__ float sv[4][32];
    __shared__ float s_in[32 * 64];
    const int tid = threadIdx.x;
    const int lane = tid & 63;
    const int w = tid >> 6;

    if (blockIdx.x < GW4E) {
        // ---- edge path (wave per node, 4 bf16 rows per instruction) ----
        const int node = __builtin_amdgcn_readfirstlane(blockIdx.x * 4 + w);
        const int beg = node << 6;
        const int cnt = deg[node];
        const int g = lane >> 4;            // row group 0..3
        const int c = lane & 15;            // uint index (2 bf16 cols)

        float ax = 0.0f, ay = 0.0f;
        {
            int eidv[8];
#pragma unroll
            for (int j = 0; j < 8; ++j) eidv[j] = csr_eid[beg + 4 * j + g];
            unsigned uv[8];
#pragma unroll
            for (int j = 0; j < 8; ++j)
                uv[j] = *(const unsigned*)(efh + (size_t)eidv[j] * 32 + 2 * c);
#pragma unroll
            for (int j = 0; j < 8; ++j)
                if (4 * j + g < cnt) {
                    ax += __uint_as_float(uv[j] << 16);
                    ay += __uint_as_float(uv[j] & 0xffff0000u);
                }
        }
        if (cnt > 32) {                     // rare, wave-uniform
            int eidv[8];
#pragma unroll
            for (int j = 0; j < 8; ++j) eidv[j] = csr_eid[beg + 32 + 4 * j + g];
            unsigned uv[8];
#pragma unroll
            for (int j = 0; j < 8; ++j)
                uv[j] = *(const unsigned*)(efh + (size_t)eidv[j] * 32 + 2 * c);
#pragma unroll
            for (int j = 0; j < 8; ++j)
                if (32 + 4 * j + g < cnt) {
                    ax += __uint_as_float(uv[j] << 16);
                    ay += __uint_as_float(uv[j] & 0xffff0000u);
                }
        }
        ax += __shfl_down(ax, 16); ay += __shfl_down(ay, 16);
        ax += __shfl_down(ax, 32); ay += __shfl_down(ay, 32);
        if (lane < 16) {
            float im = inv_mean[node];
            float2 o; o.x = ax * im; o.y = ay * im;
            *(float2*)&sv[w][2 * c] = o;    // wave-internal LDS: lgkmcnt ordered
        }
        int col = lane & 31;
        float s = 0.0f;
#pragma unroll 8
        for (int k = 0; k < 32; ++k)
            s = fmaf(sv[w][k], We[k * 32 + col], s);
        if (lane < 32) {
            float v = fmaxf(s + be[col] * bcoef[node], 0.0f) * inv_out[node];
            h0[(size_t)node * 128 + col] = f2b(v);
        }
        return;
    }

    // ---- node GEMM path (64 -> 96), 32 rows per block ----
    const int row0 = (blockIdx.x - GW4E) * 32;
    for (int i = tid; i < 512; i += 256) {      // 32 rows x 16 float4
        int m = i >> 4;
        int kv = i & 15;
        int row = min(row0 + m, n - 1);
        float4 v = *(const float4*)(nf + (size_t)row * 64 + kv * 4);
        *(float4*)(s_in + m * 64 + kv * 4) = v;
    }
    __syncthreads();

    int f0 = lane, f1 = lane + 64;
    bool fok1 = (f1 < 96);
    int ff1 = fok1 ? f1 : 0;
    float bv0 = bn[f0], bv1 = bn[ff1];

    const float* s_my = s_in + w * 8 * 64;
    float acc0[8], acc1[8];
#pragma unroll
    for (int m = 0; m < 8; ++m) { acc0[m] = 0.0f; acc1[m] = 0.0f; }

    for (int k = 0; k < 64; k += 4) {
        float wv[4][2];
#pragma unroll
        for (int j = 0; j < 4; ++j) {
            wv[j][0] = Wn[(k + j) * 96 + f0];
            wv[j][1] = Wn[(k + j) * 96 + ff1];
        }
#pragma unroll
        for (int m = 0; m < 8; ++m) {
            float4 a = *(const float4*)(s_my + m * 64 + k);
            acc0[m] = fmaf(a.x, wv[0][0], acc0[m]);
            acc0[m] = fmaf(a.y, wv[1][0], acc0[m]);
            acc0[m] = fmaf(a.z, wv[2][0], acc0[m]);
            acc0[m] = fmaf(a.w, wv[3][0], acc0[m]);
            acc1[m] = fmaf(a.x, wv[0][1], acc1[m]);
            acc1[m] = fmaf(a.y, wv[1][1], acc1[m]);
            acc1[m] = fmaf(a.z, wv[2][1], acc1[m]);
            acc1[m] = fmaf(a.w, wv[3][1], acc1[m]);
        }
    }

#pragma unroll
    for (int m = 0; m < 8; ++m) {
        int row = row0 + w * 8 + m;
        if (row < n) {
            float pm = inv_out[row];
            float v0 = fmaxf(acc0[m] + bv0, 0.0f) * pm;
            h0[(size_t)row * 128 + 32 + f0] = f2b(v0);
            if (fok1) {
                float v1 = fmaxf(acc1[m] + bv1, 0.0f) * pm;
                h0[(size_t)row * 128 + 32 + f1] = f2b(v1);
            }
        }
    }
}

// ---------------- bf16 gather, wave-per-node, 16-deep batches (r5-proven) ---------------
// agg[d] = bf16( inv_in[d] * sum_e h[src_e] );  h pre-scaled by inv_out.
template <int D, int LPT>
__global__ __launch_bounds__(256) void gather_b2_k(
    const u16* __restrict__ h, const int* __restrict__ csr,
    const int* __restrict__ deg, const float* __restrict__ inv_in,
    u16* __restrict__ agg) {
    constexpr int ACT = D / LPT;
    constexpr int NW = LPT / 2;          // uints per lane-load
    const int lane = threadIdx.x & 63;
    const int node = __builtin_amdgcn_readfirstlane(blockIdx.x * 4 + (threadIdx.x >> 6));
    const int beg = node << 6;
    const int cnt = deg[node];
    const int off = (lane < ACT ? lane : ACT - 1) * LPT;

    float acc[LPT];
#pragma unroll
    for (int j = 0; j < LPT; ++j) acc[j] = 0.0f;

    const int nb = cnt >> 4;
    int idx[16];
    if (nb > 0) {
#pragma unroll
        for (int j = 0; j < 16; ++j) idx[j] = csr[beg + j];
    }
    for (int b = 0; b < nb; ++b) {
        unsigned lv[16][NW];
#pragma unroll
        for (int j = 0; j < 16; ++j) {
            const unsigned* p = (const unsigned*)(h + (size_t)idx[j] * D + off);
            if constexpr (NW == 2) {
                uint2 t = *(const uint2*)p;
                lv[j][0] = t.x; lv[j][1] = t.y;
            } else {
                lv[j][0] = *p;
            }
        }
        int nidx[16];
        const int nbase = beg + (b + 1) * 16;
        if (b + 1 < nb) {
#pragma unroll
            for (int j = 0; j < 16; ++j) nidx[j] = csr[nbase + j];
        }
#pragma unroll
        for (int j = 0; j < 16; ++j)
#pragma unroll
            for (int q = 0; q < NW; ++q) {
                unsigned u = lv[j][q];
                acc[2 * q]     += __uint_as_float(u << 16);
                acc[2 * q + 1] += __uint_as_float(u & 0xffff0000u);
            }
        if (b + 1 < nb) {
#pragma unroll
            for (int j = 0; j < 16; ++j) idx[j] = nidx[j];
        }
    }

    int tb = beg + (nb << 4);
    int rem = cnt & 15;
    if (rem >= 8) {
        int ti[8];
#pragma unroll
        for (int j = 0; j < 8; ++j) ti[j] = csr[tb + j];
        unsigned lv[8][NW];
#pragma unroll
        for (int j = 0; j < 8; ++j) {
            const unsigned* p = (const unsigned*)(h + (size_t)ti[j] * D + off);
            if constexpr (NW == 2) {
                uint2 t = *(const uint2*)p;
                lv[j][0] = t.x; lv[j][1] = t.y;
            } else {
                lv[j][0] = *p;
            }
        }
#pragma unroll
        for (int j = 0; j < 8; ++j)
#pragma unroll
            for (int q = 0; q < NW; ++q) {
                unsigned u = lv[j][q];
                acc[2 * q]     += __uint_as_float(u << 16);
                acc[2 * q + 1] += __uint_as_float(u & 0xffff0000u);
            }
        tb += 8;
        rem -= 8;
    }
    for (int t = 0; t < rem; ++t) {
        const unsigned* p = (const unsigned*)(h + (size_t)csr[tb + t] * D + off);
#pragma unroll
        for (int q = 0; q < NW; ++q) {
            unsigned u = p[q];
            acc[2 * q]     += __uint_as_float(u << 16);
            acc[2 * q + 1] += __uint_as_float(u & 0xffff0000u);
        }
    }

    if (lane < ACT) {
        float sc = inv_in[node];
        unsigned o[NW];
#pragma unroll
        for (int q = 0; q < NW; ++q)
            o[q] = (unsigned)f2b(acc[2 * q] * sc) | ((unsigned)f2b(acc[2 * q + 1] * sc) << 16);
        unsigned* dp = (unsigned*)(agg + (size_t)node * D + off);
        if constexpr (NW == 2) {
            uint2 t; t.x = o[0]; t.y = o[1];
            *(uint2*)dp = t;
        } else {
            *dp = o[0];
        }
    }
}

// ---------------- MFMA GEMM (conv0): h1 = bf16( relu(A@W + b) * inv_out ) ----------------
template <int K>
__global__ __launch_bounds__(256) void mfma_gemm_k(
    const u16* __restrict__ A, const u16* __restrict__ Wp,
    const float* __restrict__ bias, const float* __restrict__ posts,
    u16* __restrict__ outB, int n) {
    constexpr int KS = K / 32;
    const int tid = threadIdx.x;
    const int lane = tid & 63;
    const int w = tid >> 6;
    const int row0 = blockIdx.x * 16;
    const int arow = row0 + (lane & 15);
    const int kbase = (lane >> 4) * 8;

    f4_t acc[3];
#pragma unroll
    for (int o = 0; o < 3; ++o) acc[o] = (f4_t){0.f, 0.f, 0.f, 0.f};

    const u16* ap = A + (size_t)arow * K + kbase;
#pragma unroll
    for (int s = 0; s < KS; ++s) {
        bf8_t af = *(const bf8_t*)(ap + s * 32);
#pragma unroll
        for (int o = 0; o < 3; ++o) {
            int t = w * 3 + o;
            bf8_t bf = *(const bf8_t*)(Wp + (size_t)((t * KS + s) * 64 + lane) * 8);
            acc[o] = __builtin_amdgcn_mfma_f32_16x16x32_bf16(af, bf, acc[o], 0, 0, 0);
        }
    }

    const int drow = row0 + (lane >> 4) * 4;
    const int dcol = lane & 15;
    float pm[4];
#pragma unroll
    for (int r = 0; r < 4; ++r) pm[r] = posts[drow + r];
#pragma unroll
    for (int o = 0; o < 3; ++o) {
        int col = (w * 3 + o) * 16 + dcol;
        float bv = bias[col];
#pragma unroll
        for (int r = 0; r < 4; ++r) {
            float v = fmaxf(acc[o][r] + bv, 0.0f) * pm[r];
            outB[(size_t)(drow + r) * 192 + col] = f2b(v);
        }
    }
}

// ---------------- fused MFMA: conv1 GEMM + linear GEMM + head (192->192->192->2) ---------
__global__ __launch_bounds__(256) void mfma_fused_k(
    const u16* __restrict__ A,  // [n,192] bf16 (inv_in pre-scaled)
    const u16* __restrict__ Wp1, const float* __restrict__ b1,
    const u16* __restrict__ Wp2, const float* __restrict__ b2,
    const float* __restrict__ Wo, const float* __restrict__ bo,
    float* __restrict__ out, int n) {
    constexpr int KS = 6;       // 192/32
    constexpr int S = 200;      // LDS row stride
    __shared__ float sbuf[16 * S];
    __shared__ float s_head[16][17][2];

    const int tid = threadIdx.x;
    const int lane = tid & 63;
    const int w = tid >> 6;
    const int row0 = blockIdx.x * 16;
    const int arow = row0 + (lane & 15);
    const int kbase = (lane >> 4) * 8;
    const int drow = (lane >> 4) * 4;
    const int dcol = lane & 15;

    f4_t acc[3];
#pragma unroll
    for (int o = 0; o < 3; ++o) acc[o] = (f4_t){0.f, 0.f, 0.f, 0.f};

    // ---- GEMM 1: A (global bf16) @ W1 ----
    const u16* ap = A + (size_t)arow * 192 + kbase;
#pragma unroll
    for (int s = 0; s < KS; ++s) {
        bf8_t af = *(const bf8_t*)(ap + s * 32);
#pragma unroll
        for (int o = 0; o < 3; ++o) {
            int t = w * 3 + o;
            bf8_t bf = *(const bf8_t*)(Wp1 + (size_t)((t * KS + s) * 64 + lane) * 8);
            acc[o] = __builtin_amdgcn_mfma_f32_16x16x32_bf16(af, bf, acc[o], 0, 0, 0);
        }
    }

    // h2 = relu(acc + b1) -> LDS (bf16)
    u16* h2 = (u16*)sbuf;
#pragma unroll
    for (int o = 0; o < 3; ++o) {
        int col = (w * 3 + o) * 16 + dcol;
        float bv = b1[col];
#pragma unroll
        for (int r = 0; r < 4; ++r)
            h2[(drow + r) * S + col] = f2b(fmaxf(acc[o][r] + bv, 0.0f));
    }
    __syncthreads();

    // ---- GEMM 2: h2 (LDS bf16) @ W2 ----
#pragma unroll
    for (int o = 0; o < 3; ++o) acc[o] = (f4_t){0.f, 0.f, 0.f, 0.f};
    const u16* hp = h2 + (lane & 15) * S + kbase;
#pragma unroll
    for (int s = 0; s < KS; ++s) {
        bf8_t af = *(const bf8_t*)(hp + s * 32);
#pragma unroll
        for (int o = 0; o < 3; ++o) {
            int t = w * 3 + o;
            bf8_t bf = *(const bf8_t*)(Wp2 + (size_t)((t * KS + s) * 64 + lane) * 8);
            acc[o] = __builtin_amdgcn_mfma_f32_16x16x32_bf16(af, bf, acc[o], 0, 0, 0);
        }
    }
    __syncthreads();  // all h2 reads done before overwriting sbuf as f32

    // h3 = relu(acc + b2) -> LDS (f32)
#pragma unroll
    for (int o = 0; o < 3; ++o) {
        int col = (w * 3 + o) * 16 + dcol;
        float bv = b2[col];
#pragma unroll
        for (int r = 0; r < 4; ++r)
            sbuf[(drow + r) * S + col] = fmaxf(acc[o][r] + bv, 0.0f);
    }
    __syncthreads();

    // ---- head: out = h3 @ Wo + bo ----
    {
        int r = tid >> 4;
        int seg = tid & 15;
        const float* hr = sbuf + r * S + seg * 12;
        const float* wor = Wo + seg * 24;
        float p0 = 0.0f, p1 = 0.0f;
#pragma unroll
        for (int c = 0; c < 12; ++c) {
            float hv = hr[c];
            p0 = fmaf(hv, wor[c * 2 + 0], p0);
            p1 = fmaf(hv, wor[c * 2 + 1], p1);
        }
        s_head[r][seg][0] = p0;
        s_head[r][seg][1] = p1;
    }
    __syncthreads();
    if (tid < 32) {
        int r = tid >> 1, c = tid & 1;
        float sum = bo[c];
#pragma unroll
        for (int g = 0; g < 16; ++g) sum += s_head[r][g][c];
        int row = row0 + r;
        if (row < n) out[(size_t)row * 2 + c] = sum;
    }
}

extern "C" void kernel_launch(void* const* d_in, const int* in_sizes, int n_in,
                              void* d_out, int out_size, void* d_ws, size_t ws_size,
                              hipStream_t stream) {
    const float* node_feats = (const float*)d_in[0];   // [N,64]
    const float* edge_feats = (const float*)d_in[1];   // [E,32]
    const float* Wn  = (const float*)d_in[2];          // [64,96]
    const float* bn  = (const float*)d_in[3];
    const float* We  = (const float*)d_in[4];          // [32,32]
    const float* be  = (const float*)d_in[5];
    const float* Wc0 = (const float*)d_in[6];          // [128,192]
    const float* bc0 = (const float*)d_in[7];
    const float* Wc1 = (const float*)d_in[8];          // [192,192]
    const float* bc1 = (const float*)d_in[9];
    const float* Wl0 = (const float*)d_in[10];         // [192,192]
    const float* bl0 = (const float*)d_in[11];
    const float* Wo  = (const float*)d_in[12];         // [192,2]
    const float* bo  = (const float*)d_in[13];
    const int* src = (const int*)d_in[14];
    const int* dst = (const int*)d_in[15];
    float* out = (float*)d_out;

    const int N = NN, E = NE;

    // ---- workspace layout (16B-aligned sections) ----
    int* dout      = (int*)d_ws;               // N (zeroed) -> deg_out
    int* bktc      = dout + N;                 // NBKT_PAD (zeroed) -> bucket cursors
    int* din       = bktc + NBKT_PAD;          // N deg_in (written by fill_k)
    int* csr_src   = din + N;                  // CAP*N ints (padded CSR, src ids)
    int* csr_eid   = csr_src + (size_t)CAP * N;// CAP*N ints (padded CSR, edge ids; 0-pad)
    float* inv_in   = (float*)(csr_eid + (size_t)CAP * N);  // N
    float* inv_out  = inv_in + N;              // N
    float* inv_mean = inv_out + N;             // N
    float* bcoef    = inv_mean + N;            // N
    u16* h0   = (u16*)(bcoef + N);             // [N,128] bf16 (x inv_out)
    u16* aggA = h0 + (size_t)128 * N;          // [N,128] bf16 (x inv_in)
    u16* h1   = aggA + (size_t)128 * N;        // [N,192] bf16 (x inv_out)
    u16* aggB = h1 + (size_t)192 * N;          // [N,192] bf16 (x inv_in)
    u16* Wp0  = aggB + (size_t)192 * N;        // 128*192
    u16* Wp1  = Wp0 + 128 * 192;               // 192*192
    u16* Wp2  = Wp1 + 192 * 192;               // 192*192
    u16* efh  = Wp2 + 192 * 192;               // [E,32] bf16 (51.2 MB)
    // partition buffer (9.6 MB u64) aliases h1 (19.2 MB): consumed by fill_k long
    // before mfma_gemm_k writes h1. h1 offset is a 16B multiple -> u64-aligned.
    u64* part = (u64*)h1;

    hipMemsetAsync(d_ws, 0, (size_t)(N + NBKT_PAD) * sizeof(int), stream);

    const int PBLK = (E + CHUNK - 1) / CHUNK;  // 196 partition blocks
    const int GB16 = N / 16;                   // mfma grid (3125, exact)
    const int GB32 = (N + 31) / 32;            // node-GEMM blocks (1563)

    // partition + weight pack + ef->bf16 convert (one launch, disjoint block ranges)
    partition_pack_k<<<dim3(PBLK + 48 + CONVB), dim3(256), 0, stream>>>(
        src, dst, dout, bktc, part, E, Wc0, Wc1, Wl0, Wp0, Wp1, Wp2, edge_feats, efh);
    // per-bucket CSR fill + inv scalars
    fill_k<<<dim3(NBKT), dim3(256), 0, stream>>>(part, bktc, dout, csr_src, csr_eid,
                                                 din, inv_in, inv_out, inv_mean, bcoef, N);

    // edge layer (wave-per-node bf16 gather + We) | node GEMM (64->96) -- one launch
    edge_node_k<<<dim3(GW4E + GB32), dim3(256), 0, stream>>>(
        efh, csr_eid, din, inv_mean, bcoef, inv_out, We, be,
        node_feats, Wn, bn, h0, N);

    // conv0: standalone gather (full concurrency) + MFMA GEMM 128->192
    gather_b2_k<128, 2><<<dim3(GW4E), dim3(256), 0, stream>>>(h0, csr_src, din, inv_in, aggA);
    mfma_gemm_k<128><<<dim3(GB16), dim3(256), 0, stream>>>(aggA, Wp0, bc0, inv_out, h1, N);

    // conv1: standalone gather + fused MFMA (conv1 + linear + head)
    gather_b2_k<192, 4><<<dim3(GW4E), dim3(256), 0, stream>>>(h1, csr_src, din, inv_in, aggB);
    mfma_fused_k<<<dim3(GB16), dim3(256), 0, stream>>>(aggB, Wp1, bc1, Wp2, bl0, Wo, bo,
                                                       out, N);
}